// Round 2
// baseline (293.266 us; speedup 1.0000x reference)
//
#include <hip/hip_runtime.h>

typedef unsigned int uint32;
typedef unsigned short u16;

#define B_   64
#define P1_  15
#define P2_  14
#define S_   210            // P1*P2
#define NT_  (B_*S_)        // 13440 tokens
#define E_   512
#define NH_  8
#define HD_  64

// ---------- bf16 helpers (avoid __hip_bfloat16 ABI differences) ----------
__device__ __forceinline__ u16 f2bf(float f) {
    uint32 u = __float_as_uint(f);
    u += 0x7fffu + ((u >> 16) & 1u);      // round-to-nearest-even
    return (u16)(u >> 16);
}
__device__ __forceinline__ float bf2f(u16 h) {
    return __uint_as_float(((uint32)h) << 16);
}

// ---------- shared mode-product: y[a,c,d] = ((x ×0 W0) ×1 W1) ×2 W2 + bias ----------
// xs layout: xs[m0*66 + m1*8 + m2]
// t1 layout: t1[a*68 + y*8 + z]
// t2 layout: t2[(a*8+c)*9 + z]
// thread t in [0,64): stage1 t=(y,z); stage2 t=(a,z); stage3 t=(a,c)
__device__ __forceinline__ void mode_proj(
        const float* xs, float* t1, float* t2,
        const float* __restrict__ W0, const float* __restrict__ W1,
        const float* __restrict__ W2, const float* __restrict__ bb,
        int t, float* y3)
{
    {   // stage 1: contract mode0 with W0[a,x]
        float xv[8];
        #pragma unroll
        for (int i = 0; i < 8; ++i) xv[i] = xs[i*66 + t];
        #pragma unroll
        for (int a = 0; a < 8; ++a) {
            float acc = 0.f;
            #pragma unroll
            for (int i = 0; i < 8; ++i) acc = fmaf(W0[a*8+i], xv[i], acc);
            t1[a*68 + t] = acc;
        }
    }
    __syncthreads();
    {   // stage 2: contract mode1 with W1[c,y]
        const int a = t >> 3, z = t & 7;
        float yv[8];
        #pragma unroll
        for (int y = 0; y < 8; ++y) yv[y] = t1[a*68 + y*8 + z];
        #pragma unroll
        for (int c = 0; c < 8; ++c) {
            float acc = 0.f;
            #pragma unroll
            for (int y = 0; y < 8; ++y) acc = fmaf(W1[c*8+y], yv[y], acc);
            t2[(a*8 + c)*9 + z] = acc;
        }
    }
    __syncthreads();
    {   // stage 3: contract mode2 with W2[d,z], add bias
        float zv[8];
        #pragma unroll
        for (int z = 0; z < 8; ++z) zv[z] = t2[t*9 + z];
        #pragma unroll
        for (int d = 0; d < 8; ++d) {
            float acc = bb[t*8 + d];
            #pragma unroll
            for (int z = 0; z < 8; ++z) acc = fmaf(W2[d*8+z], zv[z], acc);
            y3[d] = acc;
        }
    }
}

// ---------- kernel 1: Q,K,V projections, write bf16 [b, head, tok, dim] ----------
__global__ __launch_bounds__(64) void k_qkv(
    const float* __restrict__ x,
    const float* __restrict__ Wq0, const float* __restrict__ Wq1,
    const float* __restrict__ Wq2, const float* __restrict__ bq,
    const float* __restrict__ Wk0, const float* __restrict__ Wk1,
    const float* __restrict__ Wk2, const float* __restrict__ bk,
    const float* __restrict__ Wv0, const float* __restrict__ Wv1,
    const float* __restrict__ Wv2, const float* __restrict__ bv,
    u16* __restrict__ Qo, u16* __restrict__ Ko, u16* __restrict__ Vo)
{
    __shared__ float xs[8*66];
    __shared__ float t1[8*68];
    __shared__ float t2[64*9];
    const int tok = blockIdx.x;
    const int t   = threadIdx.x;
    const int b   = tok / S_;
    const int s   = tok - b * S_;

    const float* xp = x + (size_t)tok * E_;
    #pragma unroll
    for (int k = 0; k < 8; ++k) xs[k*66 + t] = xp[k*64 + t];
    __syncthreads();

    // head decomposition for this thread's outputs (a,c) = (t>>3, t&7)
    const int a  = t >> 3, c = t & 7;
    const int x_ = a >> 1, h1 = a & 1;
    const int y_ = c >> 1, h2 = c & 1;

    float y3[8];

    // ---- Q ----
    mode_proj(xs, t1, t2, Wq0, Wq1, Wq2, bq, t, y3);
    #pragma unroll
    for (int h3 = 0; h3 < 2; ++h3) {
        const int h = (((h1 << 1) | h2) << 1) | h3;
        ushort4 w;
        w.x = f2bf(y3[0 + h3]); w.y = f2bf(y3[2 + h3]);
        w.z = f2bf(y3[4 + h3]); w.w = f2bf(y3[6 + h3]);
        *reinterpret_cast<ushort4*>(
            Qo + ((size_t)(b*NH_ + h)*S_ + s)*HD_ + (x_*16 + y_*4)) = w;
    }
    // ---- K ----
    mode_proj(xs, t1, t2, Wk0, Wk1, Wk2, bk, t, y3);
    #pragma unroll
    for (int h3 = 0; h3 < 2; ++h3) {
        const int h = (((h1 << 1) | h2) << 1) | h3;
        ushort4 w;
        w.x = f2bf(y3[0 + h3]); w.y = f2bf(y3[2 + h3]);
        w.z = f2bf(y3[4 + h3]); w.w = f2bf(y3[6 + h3]);
        *reinterpret_cast<ushort4*>(
            Ko + ((size_t)(b*NH_ + h)*S_ + s)*HD_ + (x_*16 + y_*4)) = w;
    }
    // ---- V ----
    mode_proj(xs, t1, t2, Wv0, Wv1, Wv2, bv, t, y3);
    #pragma unroll
    for (int h3 = 0; h3 < 2; ++h3) {
        const int h = (((h1 << 1) | h2) << 1) | h3;
        ushort4 w;
        w.x = f2bf(y3[0 + h3]); w.y = f2bf(y3[2 + h3]);
        w.z = f2bf(y3[4 + h3]); w.w = f2bf(y3[6 + h3]);
        *reinterpret_cast<ushort4*>(
            Vo + ((size_t)(b*NH_ + h)*S_ + s)*HD_ + (x_*16 + y_*4)) = w;
    }
}

// ---------- kernel 2: attention per (b,head); 1 query per thread ----------
__global__ __launch_bounds__(256) void k_attn(
    const u16* __restrict__ Q, const u16* __restrict__ K,
    const u16* __restrict__ V, u16* __restrict__ O)
{
    __shared__ __align__(16) float Ks[70*64];
    __shared__ __align__(16) float Vs[70*64];
    const int bh  = blockIdx.x;
    const int tid = threadIdx.x;
    const bool active = tid < S_;
    const int iq = active ? tid : (S_ - 1);

    // load this thread's query, pre-scaled by 64^-0.5 = 0.125
    float q[64];
    {
        const uint4* qp = reinterpret_cast<const uint4*>(Q + ((size_t)bh*S_ + iq)*HD_);
        #pragma unroll
        for (int c8 = 0; c8 < 8; ++c8) {
            uint4 u = qp[c8];
            q[c8*8+0]=bf2f((u16)(u.x&0xffffu))*0.125f; q[c8*8+1]=bf2f((u16)(u.x>>16))*0.125f;
            q[c8*8+2]=bf2f((u16)(u.y&0xffffu))*0.125f; q[c8*8+3]=bf2f((u16)(u.y>>16))*0.125f;
            q[c8*8+4]=bf2f((u16)(u.z&0xffffu))*0.125f; q[c8*8+5]=bf2f((u16)(u.z>>16))*0.125f;
            q[c8*8+6]=bf2f((u16)(u.w&0xffffu))*0.125f; q[c8*8+7]=bf2f((u16)(u.w>>16))*0.125f;
        }
    }

    float l = 0.f;
    float o[64];
    #pragma unroll
    for (int d = 0; d < 64; ++d) o[d] = 0.f;

    // logits are provably tiny (|s| < ~0.01): softmax with fixed shift 0 is exact math
    for (int tile = 0; tile < 3; ++tile) {
        __syncthreads();
        {   // stage 70 keys + values (bf16 -> f32) into LDS
            const uint4* kp = reinterpret_cast<const uint4*>(K + ((size_t)bh*S_ + tile*70)*HD_);
            const uint4* vp = reinterpret_cast<const uint4*>(V + ((size_t)bh*S_ + tile*70)*HD_);
            for (int cc = tid; cc < 560; cc += 256) {
                uint4 u = kp[cc];
                float* dst = &Ks[cc*8];
                dst[0]=bf2f((u16)(u.x&0xffffu)); dst[1]=bf2f((u16)(u.x>>16));
                dst[2]=bf2f((u16)(u.y&0xffffu)); dst[3]=bf2f((u16)(u.y>>16));
                dst[4]=bf2f((u16)(u.z&0xffffu)); dst[5]=bf2f((u16)(u.z>>16));
                dst[6]=bf2f((u16)(u.w&0xffffu)); dst[7]=bf2f((u16)(u.w>>16));
                u = vp[cc];
                dst = &Vs[cc*8];
                dst[0]=bf2f((u16)(u.x&0xffffu)); dst[1]=bf2f((u16)(u.x>>16));
                dst[2]=bf2f((u16)(u.y&0xffffu)); dst[3]=bf2f((u16)(u.y>>16));
                dst[4]=bf2f((u16)(u.z&0xffffu)); dst[5]=bf2f((u16)(u.z>>16));
                dst[6]=bf2f((u16)(u.w&0xffffu)); dst[7]=bf2f((u16)(u.w>>16));
            }
        }
        __syncthreads();
        if (active) {
            for (int j = 0; j < 70; ++j) {
                const float4* kr = reinterpret_cast<const float4*>(&Ks[j*64]);
                float s0 = 0.f, s1 = 0.f, s2 = 0.f, s3 = 0.f;
                #pragma unroll
                for (int d4 = 0; d4 < 16; d4 += 4) {
                    float4 A = kr[d4+0], Bv = kr[d4+1], C = kr[d4+2], D = kr[d4+3];
                    s0 = fmaf(q[(d4+0)*4+0],A.x,fmaf(q[(d4+0)*4+1],A.y,fmaf(q[(d4+0)*4+2],A.z,fmaf(q[(d4+0)*4+3],A.w,s0))));
                    s1 = fmaf(q[(d4+1)*4+0],Bv.x,fmaf(q[(d4+1)*4+1],Bv.y,fmaf(q[(d4+1)*4+2],Bv.z,fmaf(q[(d4+1)*4+3],Bv.w,s1))));
                    s2 = fmaf(q[(d4+2)*4+0],C.x,fmaf(q[(d4+2)*4+1],C.y,fmaf(q[(d4+2)*4+2],C.z,fmaf(q[(d4+2)*4+3],C.w,s2))));
                    s3 = fmaf(q[(d4+3)*4+0],D.x,fmaf(q[(d4+3)*4+1],D.y,fmaf(q[(d4+3)*4+2],D.z,fmaf(q[(d4+3)*4+3],D.w,s3))));
                }
                const float p = __expf((s0 + s1) + (s2 + s3));
                l += p;
                const float4* vr = reinterpret_cast<const float4*>(&Vs[j*64]);
                #pragma unroll
                for (int d4 = 0; d4 < 16; ++d4) {
                    float4 v4 = vr[d4];
                    o[d4*4+0] = fmaf(p, v4.x, o[d4*4+0]);
                    o[d4*4+1] = fmaf(p, v4.y, o[d4*4+1]);
                    o[d4*4+2] = fmaf(p, v4.z, o[d4*4+2]);
                    o[d4*4+3] = fmaf(p, v4.w, o[d4*4+3]);
                }
            }
        }
    }

    if (active) {
        const float inv = 1.0f / l;
        u16* op = O + ((size_t)bh*S_ + iq)*HD_;
        #pragma unroll
        for (int c8 = 0; c8 < 8; ++c8) {
            uint4 w;
            w.x = (uint32)f2bf(o[c8*8+0]*inv) | ((uint32)f2bf(o[c8*8+1]*inv) << 16);
            w.y = (uint32)f2bf(o[c8*8+2]*inv) | ((uint32)f2bf(o[c8*8+3]*inv) << 16);
            w.z = (uint32)f2bf(o[c8*8+4]*inv) | ((uint32)f2bf(o[c8*8+5]*inv) << 16);
            w.w = (uint32)f2bf(o[c8*8+6]*inv) | ((uint32)f2bf(o[c8*8+7]*inv) << 16);
            reinterpret_cast<uint4*>(op)[c8] = w;
        }
    }
}

// ---------- kernel 3: gather heads -> output projection -> f32 out ----------
__global__ __launch_bounds__(64) void k_oproj(
    const u16* __restrict__ O,
    const float* __restrict__ Wo0, const float* __restrict__ Wo1,
    const float* __restrict__ Wo2, const float* __restrict__ bo,
    float* __restrict__ out)
{
    __shared__ float xs[8*66];
    __shared__ float t1[8*68];
    __shared__ float t2[64*9];
    const int tok = blockIdx.x;
    const int t   = threadIdx.x;
    const int b   = tok / S_;
    const int s   = tok - b * S_;

    const int a  = t >> 3, c = t & 7;
    const int x_ = a >> 1, h1 = a & 1;
    const int y_ = c >> 1, h2 = c & 1;
    #pragma unroll
    for (int h3 = 0; h3 < 2; ++h3) {
        const int h = (((h1 << 1) | h2) << 1) | h3;
        const ushort4 w = *reinterpret_cast<const ushort4*>(
            O + ((size_t)(b*NH_ + h)*S_ + s)*HD_ + (x_*16 + y_*4));
        xs[a*66 + c*8 + 0 + h3] = bf2f(w.x);
        xs[a*66 + c*8 + 2 + h3] = bf2f(w.y);
        xs[a*66 + c*8 + 4 + h3] = bf2f(w.z);
        xs[a*66 + c*8 + 6 + h3] = bf2f(w.w);
    }
    __syncthreads();

    float y3[8];
    mode_proj(xs, t1, t2, Wo0, Wo1, Wo2, bo, t, y3);

    // f32 output: thread t writes elements [tok*512 + t*8, +8) -- coalesced 32B/lane
    float4* op = reinterpret_cast<float4*>(out + (size_t)tok * E_ + t * 8);
    float4 u0, u1;
    u0.x = y3[0]; u0.y = y3[1]; u0.z = y3[2]; u0.w = y3[3];
    u1.x = y3[4]; u1.y = y3[5]; u1.z = y3[6]; u1.w = y3[7];
    op[0] = u0;
    op[1] = u1;
}

extern "C" void kernel_launch(void* const* d_in, const int* in_sizes, int n_in,
                              void* d_out, int out_size, void* d_ws, size_t ws_size,
                              hipStream_t stream)
{
    const float* x   = (const float*)d_in[0];
    const float* Wq0 = (const float*)d_in[1];
    const float* Wq1 = (const float*)d_in[2];
    const float* Wq2 = (const float*)d_in[3];
    const float* bq  = (const float*)d_in[4];
    const float* Wk0 = (const float*)d_in[5];
    const float* Wk1 = (const float*)d_in[6];
    const float* Wk2 = (const float*)d_in[7];
    const float* bk  = (const float*)d_in[8];
    const float* Wv0 = (const float*)d_in[9];
    const float* Wv1 = (const float*)d_in[10];
    const float* Wv2 = (const float*)d_in[11];
    const float* bv  = (const float*)d_in[12];
    const float* Wo0 = (const float*)d_in[13];
    const float* Wo1 = (const float*)d_in[14];
    const float* Wo2 = (const float*)d_in[15];
    const float* bo  = (const float*)d_in[16];

    const size_t TN = (size_t)B_ * NH_ * S_ * HD_;   // 6,881,280 elems per tensor
    u16* Q  = (u16*)d_ws;
    u16* Kt = Q  + TN;
    u16* Vt = Kt + TN;
    u16* Ot = Vt + TN;                                // total ~55 MB of d_ws

    k_qkv<<<NT_, 64, 0, stream>>>(x, Wq0, Wq1, Wq2, bq,
                                  Wk0, Wk1, Wk2, bk,
                                  Wv0, Wv1, Wv2, bv, Q, Kt, Vt);
    k_attn<<<B_*NH_, 256, 0, stream>>>(Q, Kt, Vt, Ot);
    k_oproj<<<NT_, 64, 0, stream>>>(Ot, Wo0, Wo1, Wo2, bo, (float*)d_out);
}

// Round 6
// 151.819 us; speedup vs baseline: 1.9317x; 1.9317x over previous
//
#include <hip/hip_runtime.h>

typedef unsigned int   u32;
typedef unsigned short u16;
typedef float f32x16 __attribute__((ext_vector_type(16)));
typedef short s16x8  __attribute__((ext_vector_type(8)));
typedef u32   u32x4  __attribute__((ext_vector_type(4)));
typedef u32   u32x2  __attribute__((ext_vector_type(2)));

#define B_   64
#define P1_  15
#define P2_  14
#define S_   210            // P1*P2 tokens per batch
#define SP_  224            // padded rows (7 strips of 32) for Q/K/V scratch
#define NT_  (B_*S_)        // 13440 tokens
#define E_   512
#define NH_  8
#define HD_  64
#define KSC  0.18033688011112042f   // 0.125 (=64^-0.5) * log2(e)

// ---------- bf16 helpers ----------
__device__ __forceinline__ u16 f2bf(float f) {
    u32 u = __float_as_uint(f);
    u += 0x7fffu + ((u >> 16) & 1u);      // RNE
    return (u16)(u >> 16);
}
__device__ __forceinline__ float bf2f(u16 h) {
    return __uint_as_float(((u32)h) << 16);
}

// ---------- shared mode-product: y[a,c,d] = ((x ×0 W0) ×1 W1) ×2 W2 + bias ----------
// xs[m0*66 + m1*8 + m2]; t1[a*68 + y*8 + z]; t2[(a*8+c)*9 + z]
// thread t in [0,64): stage1 t=(y,z); stage2 t=(a,z); stage3 t=(a,c)
__device__ __forceinline__ void mode_proj(
        const float* xs, float* t1, float* t2,
        const float* __restrict__ W0, const float* __restrict__ W1,
        const float* __restrict__ W2, const float* __restrict__ bb,
        int t, float* y3)
{
    {
        float xv[8];
        #pragma unroll
        for (int i = 0; i < 8; ++i) xv[i] = xs[i*66 + t];
        #pragma unroll
        for (int a = 0; a < 8; ++a) {
            float acc = 0.f;
            #pragma unroll
            for (int i = 0; i < 8; ++i) acc = fmaf(W0[a*8+i], xv[i], acc);
            t1[a*68 + t] = acc;
        }
    }
    __syncthreads();
    {
        const int a = t >> 3, z = t & 7;
        float yv[8];
        #pragma unroll
        for (int y = 0; y < 8; ++y) yv[y] = t1[a*68 + y*8 + z];
        #pragma unroll
        for (int c = 0; c < 8; ++c) {
            float acc = 0.f;
            #pragma unroll
            for (int y = 0; y < 8; ++y) acc = fmaf(W1[c*8+y], yv[y], acc);
            t2[(a*8 + c)*9 + z] = acc;
        }
    }
    __syncthreads();
    {
        float zv[8];
        #pragma unroll
        for (int z = 0; z < 8; ++z) zv[z] = t2[t*9 + z];
        #pragma unroll
        for (int d = 0; d < 8; ++d) {
            float acc = bb[t*8 + d];
            #pragma unroll
            for (int z = 0; z < 8; ++z) acc = fmaf(W2[d*8+z], zv[z], acc);
            y3[d] = acc;
        }
    }
}

// ---------- kernel 1: Q,K,V projections (4 tokens/block), bf16 [b,h,tok(SP_),dim] ----------
__global__ __launch_bounds__(256) void k_qkv(
    const float* __restrict__ x,
    const float* __restrict__ Wq0, const float* __restrict__ Wq1,
    const float* __restrict__ Wq2, const float* __restrict__ bq,
    const float* __restrict__ Wk0, const float* __restrict__ Wk1,
    const float* __restrict__ Wk2, const float* __restrict__ bk,
    const float* __restrict__ Wv0, const float* __restrict__ Wv1,
    const float* __restrict__ Wv2, const float* __restrict__ bv,
    u16* __restrict__ Qo, u16* __restrict__ Ko, u16* __restrict__ Vo)
{
    __shared__ float xs[4][528];
    __shared__ float t1[4][544];
    __shared__ float t2[4][576];
    const int w = threadIdx.x >> 6, t = threadIdx.x & 63;
    const int tok = blockIdx.x*4 + w;
    const int b   = tok / S_;
    const int s   = tok - b * S_;

    const float* xp = x + (size_t)tok * E_;
    #pragma unroll
    for (int k = 0; k < 8; ++k) xs[w][k*66 + t] = xp[k*64 + t];
    __syncthreads();

    const int a  = t >> 3, c = t & 7;
    const int x_ = a >> 1, h1 = a & 1;
    const int y_ = c >> 1, h2 = c & 1;

    float y3[8];

    mode_proj(xs[w], t1[w], t2[w], Wq0, Wq1, Wq2, bq, t, y3);
    #pragma unroll
    for (int h3 = 0; h3 < 2; ++h3) {
        const int h = (((h1 << 1) | h2) << 1) | h3;
        ushort4 v;
        v.x = f2bf(y3[0 + h3]); v.y = f2bf(y3[2 + h3]);
        v.z = f2bf(y3[4 + h3]); v.w = f2bf(y3[6 + h3]);
        *reinterpret_cast<ushort4*>(
            Qo + ((size_t)(b*NH_ + h)*SP_ + s)*HD_ + (x_*16 + y_*4)) = v;
    }
    mode_proj(xs[w], t1[w], t2[w], Wk0, Wk1, Wk2, bk, t, y3);
    #pragma unroll
    for (int h3 = 0; h3 < 2; ++h3) {
        const int h = (((h1 << 1) | h2) << 1) | h3;
        ushort4 v;
        v.x = f2bf(y3[0 + h3]); v.y = f2bf(y3[2 + h3]);
        v.z = f2bf(y3[4 + h3]); v.w = f2bf(y3[6 + h3]);
        *reinterpret_cast<ushort4*>(
            Ko + ((size_t)(b*NH_ + h)*SP_ + s)*HD_ + (x_*16 + y_*4)) = v;
    }
    mode_proj(xs[w], t1[w], t2[w], Wv0, Wv1, Wv2, bv, t, y3);
    #pragma unroll
    for (int h3 = 0; h3 < 2; ++h3) {
        const int h = (((h1 << 1) | h2) << 1) | h3;
        ushort4 v;
        v.x = f2bf(y3[0 + h3]); v.y = f2bf(y3[2 + h3]);
        v.z = f2bf(y3[4 + h3]); v.w = f2bf(y3[6 + h3]);
        *reinterpret_cast<ushort4*>(
            Vo + ((size_t)(b*NH_ + h)*SP_ + s)*HD_ + (x_*16 + y_*4)) = v;
    }
}

// ---------- kernel 2: MFMA attention, one block per (b,h), 8 waves, 1 strip/wave ----------
// S^T tile = mfma(A=K, B=Q): D col = query (lane&31), row = key (reg pattern)
// O  tile  = mfma(A=P, B=V): D col = dim   (lane&31), row = query
__global__ __launch_bounds__(512, 2) void k_attn(
    const u16* __restrict__ Q, const u16* __restrict__ K,
    const u16* __restrict__ V, u16* __restrict__ O)
{
    __shared__ u16   Kl[SP_*64];     // row-major, 16B-block XOR-swizzled: blk c -> c ^ (row&7)
    __shared__ u16   Vt[64*232];     // transposed [dim][tok], token stride padded to 232
    __shared__ float invl[8*32];

    const int bh  = blockIdx.x;
    const int tid = threadIdx.x;
    const u16* Qg = Q + (size_t)bh*SP_*HD_;
    const u16* Kg = K + (size_t)bh*SP_*HD_;
    const u16* Vg = V + (size_t)bh*SP_*HD_;

    // ---- stage K (swizzled 16B blocks; 1792 blocks of 16B) ----
    #pragma unroll
    for (int i = 0; i < 4; ++i) {
        int sIdx = i*512 + tid;
        if (sIdx < 1792) {
            int row = sIdx >> 3, cc = sIdx & 7;
            u32x4 d = *(const u32x4*)(Kg + sIdx*8);
            *(u32x4*)&Kl[row*64 + (cc ^ (row & 7))*8] = d;
        }
    }
    // ---- stage V transposed: 448 groups of (4 toks x 8 dims) ----
    if (tid < 448) {
        int tokg = tid >> 3, dg = tid & 7;
        int t0 = tokg*4, d0 = dg*8;
        u32x4 r0 = *(const u32x4*)(Vg + (size_t)(t0+0)*64 + d0);
        u32x4 r1 = *(const u32x4*)(Vg + (size_t)(t0+1)*64 + d0);
        u32x4 r2 = *(const u32x4*)(Vg + (size_t)(t0+2)*64 + d0);
        u32x4 r3 = *(const u32x4*)(Vg + (size_t)(t0+3)*64 + d0);
        #pragma unroll
        for (int j = 0; j < 8; ++j) {
            u32 sel = (j & 1) ? 0x07060302u : 0x05040100u;
            u32 lo  = __builtin_amdgcn_perm(r1[j>>1], r0[j>>1], sel);
            u32 hi2 = __builtin_amdgcn_perm(r3[j>>1], r2[j>>1], sel);
            *(u32x2*)&Vt[(d0+j)*232 + t0] = (u32x2){lo, hi2};
        }
    }
    __syncthreads();

    const int w    = tid >> 6;
    const int lane = tid & 63;
    const int l31  = lane & 31;
    const int hi   = lane >> 5;
    if (w >= 7) return;               // no barriers after this point
    const int strip = w;

    // Q B-frags for this strip (row = query = l31, k-dims contiguous)
    const u16* qb = Qg + (size_t)(strip*32 + l31)*64 + hi*8;
    const s16x8 qf0 = *(const s16x8*)(qb +  0);
    const s16x8 qf1 = *(const s16x8*)(qb + 16);
    const s16x8 qf2 = *(const s16x8*)(qb + 32);
    const s16x8 qf3 = *(const s16x8*)(qb + 48);

    f32x16 oacc0 = {}, oacc1 = {};
    float  psum  = 0.f;
    const int swz = l31 & 7;

    #pragma unroll
    for (int kt = 0; kt < 7; ++kt) {
        const u16* kbase = &Kl[(kt*32 + l31)*64];
        f32x16 sacc = {};
        s16x8 kf;
        kf = *(const s16x8*)(kbase + ((0 + hi) ^ swz)*8);
        sacc = __builtin_amdgcn_mfma_f32_32x32x16_bf16(kf, qf0, sacc, 0, 0, 0);
        kf = *(const s16x8*)(kbase + ((2 + hi) ^ swz)*8);
        sacc = __builtin_amdgcn_mfma_f32_32x32x16_bf16(kf, qf1, sacc, 0, 0, 0);
        kf = *(const s16x8*)(kbase + ((4 + hi) ^ swz)*8);
        sacc = __builtin_amdgcn_mfma_f32_32x32x16_bf16(kf, qf2, sacc, 0, 0, 0);
        kf = *(const s16x8*)(kbase + ((6 + hi) ^ swz)*8);
        sacc = __builtin_amdgcn_mfma_f32_32x32x16_bf16(kf, qf3, sacc, 0, 0, 0);

        // softmax numerators (fixed shift 0: logits are tiny)
        float p[16];
        #pragma unroll
        for (int r = 0; r < 16; ++r) p[r] = exp2f(sacc[r] * KSC);
        if (kt == 6) {                // keys 192+krow; valid < 210 <=> krow < 18
            const float hm = hi ? 0.f : 1.f;
            p[8] *= hm; p[9] *= hm;   // krow 16,17 (+4 if hi)
            p[10] = 0.f; p[11] = 0.f; p[12] = 0.f; p[13] = 0.f; p[14] = 0.f; p[15] = 0.f;
        }
        #pragma unroll
        for (int r = 0; r < 16; ++r) psum += p[r];

        // P (D-layout) -> A-frags via cvt_pk + permlane32_swap
        u32 c0, c1, c2, c3, c4, c5, c6, c7;
        asm("v_cvt_pk_bf16_f32 %0, %1, %2" : "=v"(c0) : "v"(p[0]),  "v"(p[1]));
        asm("v_cvt_pk_bf16_f32 %0, %1, %2" : "=v"(c1) : "v"(p[2]),  "v"(p[3]));
        asm("v_cvt_pk_bf16_f32 %0, %1, %2" : "=v"(c2) : "v"(p[4]),  "v"(p[5]));
        asm("v_cvt_pk_bf16_f32 %0, %1, %2" : "=v"(c3) : "v"(p[6]),  "v"(p[7]));
        asm("v_cvt_pk_bf16_f32 %0, %1, %2" : "=v"(c4) : "v"(p[8]),  "v"(p[9]));
        asm("v_cvt_pk_bf16_f32 %0, %1, %2" : "=v"(c5) : "v"(p[10]), "v"(p[11]));
        asm("v_cvt_pk_bf16_f32 %0, %1, %2" : "=v"(c6) : "v"(p[12]), "v"(p[13]));
        asm("v_cvt_pk_bf16_f32 %0, %1, %2" : "=v"(c7) : "v"(p[14]), "v"(p[15]));
        asm("v_permlane32_swap_b32 %0, %1" : "+v"(c0), "+v"(c2));
        asm("v_permlane32_swap_b32 %0, %1" : "+v"(c1), "+v"(c3));
        asm("v_permlane32_swap_b32 %0, %1" : "+v"(c4), "+v"(c6));
        asm("v_permlane32_swap_b32 %0, %1" : "+v"(c5), "+v"(c7));
        const s16x8 pf0 = __builtin_bit_cast(s16x8, (u32x4){c0, c1, c2, c3});
        const s16x8 pf1 = __builtin_bit_cast(s16x8, (u32x4){c4, c5, c6, c7});

        // PV: B-frag = 8 consecutive tokens of one dim row in Vt
        const u16* vb = &Vt[kt*32 + hi*8];
        s16x8 vf;
        vf = *(const s16x8*)(vb + (0*32 + l31)*232 +  0);
        oacc0 = __builtin_amdgcn_mfma_f32_32x32x16_bf16(pf0, vf, oacc0, 0, 0, 0);
        vf = *(const s16x8*)(vb + (0*32 + l31)*232 + 16);
        oacc0 = __builtin_amdgcn_mfma_f32_32x32x16_bf16(pf1, vf, oacc0, 0, 0, 0);
        vf = *(const s16x8*)(vb + (1*32 + l31)*232 +  0);
        oacc1 = __builtin_amdgcn_mfma_f32_32x32x16_bf16(pf0, vf, oacc1, 0, 0, 0);
        vf = *(const s16x8*)(vb + (1*32 + l31)*232 + 16);
        oacc1 = __builtin_amdgcn_mfma_f32_32x32x16_bf16(pf1, vf, oacc1, 0, 0, 0);
    }

    // ---- normalize + store (O row-major [bh][tok(S_)][dim]) ----
    float tot = psum + __shfl_xor(psum, 32, 64);
    invl[w*32 + l31] = 1.0f / tot;
    asm volatile("s_waitcnt lgkmcnt(0)" ::: "memory");

    u16* Ob = O + ((size_t)bh*S_ + strip*32)*HD_;
    #pragma unroll
    for (int r = 0; r < 16; ++r) {
        const int q = (r & 3) + 8*(r >> 2) + 4*hi;
        if (strip == 6 && q >= 18) continue;        // token >= 210
        const float iv = invl[w*32 + q];
        Ob[(size_t)q*64 + l31]      = f2bf(oacc0[r] * iv);
        Ob[(size_t)q*64 + 32 + l31] = f2bf(oacc1[r] * iv);
    }
}

// ---------- kernel 3: gather heads -> output projection -> f32 out (4 tokens/block) ----------
__global__ __launch_bounds__(256) void k_oproj(
    const u16* __restrict__ O,
    const float* __restrict__ Wo0, const float* __restrict__ Wo1,
    const float* __restrict__ Wo2, const float* __restrict__ bo,
    float* __restrict__ out)
{
    __shared__ float xs[4][528];
    __shared__ float t1[4][544];
    __shared__ float t2[4][576];
    const int w = threadIdx.x >> 6, t = threadIdx.x & 63;
    const int tok = blockIdx.x*4 + w;
    const int b   = tok / S_;
    const int s   = tok - b * S_;

    const int a  = t >> 3, c = t & 7;
    const int x_ = a >> 1, h1 = a & 1;
    const int y_ = c >> 1, h2 = c & 1;
    #pragma unroll
    for (int h3 = 0; h3 < 2; ++h3) {
        const int h = (((h1 << 1) | h2) << 1) | h3;
        const ushort4 v = *reinterpret_cast<const ushort4*>(
            O + ((size_t)(b*NH_ + h)*S_ + s)*HD_ + (x_*16 + y_*4));
        xs[w][a*66 + c*8 + 0 + h3] = bf2f(v.x);
        xs[w][a*66 + c*8 + 2 + h3] = bf2f(v.y);
        xs[w][a*66 + c*8 + 4 + h3] = bf2f(v.z);
        xs[w][a*66 + c*8 + 6 + h3] = bf2f(v.w);
    }
    __syncthreads();

    float y3[8];
    mode_proj(xs[w], t1[w], t2[w], Wo0, Wo1, Wo2, bo, t, y3);

    float4* op = reinterpret_cast<float4*>(out + (size_t)tok * E_ + t * 8);
    float4 u0, u1;
    u0.x = y3[0]; u0.y = y3[1]; u0.z = y3[2]; u0.w = y3[3];
    u1.x = y3[4]; u1.y = y3[5]; u1.z = y3[6]; u1.w = y3[7];
    op[0] = u0;
    op[1] = u1;
}

extern "C" void kernel_launch(void* const* d_in, const int* in_sizes, int n_in,
                              void* d_out, int out_size, void* d_ws, size_t ws_size,
                              hipStream_t stream)
{
    const float* x   = (const float*)d_in[0];
    const float* Wq0 = (const float*)d_in[1];
    const float* Wq1 = (const float*)d_in[2];
    const float* Wq2 = (const float*)d_in[3];
    const float* bq  = (const float*)d_in[4];
    const float* Wk0 = (const float*)d_in[5];
    const float* Wk1 = (const float*)d_in[6];
    const float* Wk2 = (const float*)d_in[7];
    const float* bk  = (const float*)d_in[8];
    const float* Wv0 = (const float*)d_in[9];
    const float* Wv1 = (const float*)d_in[10];
    const float* Wv2 = (const float*)d_in[11];
    const float* bv  = (const float*)d_in[12];
    const float* Wo0 = (const float*)d_in[13];
    const float* Wo1 = (const float*)d_in[14];
    const float* Wo2 = (const float*)d_in[15];
    const float* bo  = (const float*)d_in[16];

    const size_t TP = (size_t)B_ * NH_ * SP_ * HD_;   // padded Q/K/V tensors
    u16* Qs = (u16*)d_ws;
    u16* Ks = Qs + TP;
    u16* Vs = Ks + TP;
    u16* Os = Vs + TP;                                // O: B_*NH_*S_*HD_

    k_qkv<<<NT_/4, 256, 0, stream>>>(x, Wq0, Wq1, Wq2, bq,
                                     Wk0, Wk1, Wk2, bk,
                                     Wv0, Wv1, Wv2, bv, Qs, Ks, Vs);
    k_attn<<<B_*NH_, 512, 0, stream>>>(Qs, Ks, Vs, Os);
    k_oproj<<<NT_/4, 256, 0, stream>>>(Os, Wo0, Wo1, Wo2, bo, (float*)d_out);
}

// Round 7
// 148.704 us; speedup vs baseline: 1.9721x; 1.0209x over previous
//
#include <hip/hip_runtime.h>

typedef unsigned int   u32;
typedef unsigned short u16;
typedef float f32x16 __attribute__((ext_vector_type(16)));
typedef short s16x8  __attribute__((ext_vector_type(8)));
typedef u32   u32x4  __attribute__((ext_vector_type(4)));
typedef u32   u32x2  __attribute__((ext_vector_type(2)));

#define B_   64
#define P1_  15
#define P2_  14
#define S_   210            // P1*P2 tokens per batch
#define SP_  224            // padded rows (7 strips of 32) for Q/K/V scratch
#define NT_  (B_*S_)        // 13440 tokens
#define E_   512
#define NH_  8
#define HD_  64
#define KSC  0.18033688011112042f   // 0.125 (=64^-0.5) * log2(e)

// ---------- bf16 helpers ----------
__device__ __forceinline__ u16 f2bf(float f) {
    u32 u = __float_as_uint(f);
    u += 0x7fffu + ((u >> 16) & 1u);      // RNE
    return (u16)(u >> 16);
}
__device__ __forceinline__ float bf2f(u16 h) {
    return __uint_as_float(((u32)h) << 16);
}

// wave-local LDS fence: all exchange in mode_proj is within one wave, so a
// block barrier is overkill. In-order DS pipe + lgkmcnt(0) + compiler memory
// clobber gives the same guarantee without coupling the block's waves.
__device__ __forceinline__ void wfence() {
    asm volatile("s_waitcnt lgkmcnt(0)" ::: "memory");
}

// ---------- shared mode-product: y[a,c,d] = ((x ×0 W0) ×1 W1) ×2 W2 + bias ----------
// xs[m0*66 + m1*8 + m2]; t1[a*68 + y*8 + z]; t2[(a*8+c)*9 + z]
// thread t in [0,64): stage1 t=(y,z); stage2 t=(a,z); stage3 t=(a,c)
// All LDS slices are private to the calling wave -> wave-local fences only.
__device__ __forceinline__ void mode_proj(
        const float* xs, float* t1, float* t2,
        const float* __restrict__ W0, const float* __restrict__ W1,
        const float* __restrict__ W2, const float* __restrict__ bb,
        int t, float* y3)
{
    {
        float xv[8];
        #pragma unroll
        for (int i = 0; i < 8; ++i) xv[i] = xs[i*66 + t];
        #pragma unroll
        for (int a = 0; a < 8; ++a) {
            float acc = 0.f;
            #pragma unroll
            for (int i = 0; i < 8; ++i) acc = fmaf(W0[a*8+i], xv[i], acc);
            t1[a*68 + t] = acc;
        }
    }
    wfence();
    {
        const int a = t >> 3, z = t & 7;
        float yv[8];
        #pragma unroll
        for (int y = 0; y < 8; ++y) yv[y] = t1[a*68 + y*8 + z];
        #pragma unroll
        for (int c = 0; c < 8; ++c) {
            float acc = 0.f;
            #pragma unroll
            for (int y = 0; y < 8; ++y) acc = fmaf(W1[c*8+y], yv[y], acc);
            t2[(a*8 + c)*9 + z] = acc;
        }
    }
    wfence();
    {
        float zv[8];
        #pragma unroll
        for (int z = 0; z < 8; ++z) zv[z] = t2[t*9 + z];
        #pragma unroll
        for (int d = 0; d < 8; ++d) {
            float acc = bb[t*8 + d];
            #pragma unroll
            for (int z = 0; z < 8; ++z) acc = fmaf(W2[d*8+z], zv[z], acc);
            y3[d] = acc;
        }
    }
    wfence();   // t1/t2 reusable by next call from this wave
}

// ---------- kernel 1: Q,K,V projections (4 tokens/block), bf16 [b,h,tok(SP_),dim] ----------
__global__ __launch_bounds__(256) void k_qkv(
    const float* __restrict__ x,
    const float* __restrict__ Wq0, const float* __restrict__ Wq1,
    const float* __restrict__ Wq2, const float* __restrict__ bq,
    const float* __restrict__ Wk0, const float* __restrict__ Wk1,
    const float* __restrict__ Wk2, const float* __restrict__ bk,
    const float* __restrict__ Wv0, const float* __restrict__ Wv1,
    const float* __restrict__ Wv2, const float* __restrict__ bv,
    u16* __restrict__ Qo, u16* __restrict__ Ko, u16* __restrict__ Vo)
{
    __shared__ float xs[4][528];
    __shared__ float t1[4][544];
    __shared__ float t2[4][576];
    const int w = threadIdx.x >> 6, t = threadIdx.x & 63;
    const int tok = blockIdx.x*4 + w;
    const int b   = tok / S_;
    const int s   = tok - b * S_;

    // stage x: 2 x float4 per lane (1 KB per wave-instruction)
    const float* xp = x + (size_t)tok * E_;
    #pragma unroll
    for (int k4 = 0; k4 < 2; ++k4) {
        const float4 vv = *reinterpret_cast<const float4*>(xp + k4*256 + t*4);
        const int m0 = k4*4 + (t >> 4);
        const int in = (t*4) & 63;
        xs[w][m0*66 + in + 0] = vv.x;
        xs[w][m0*66 + in + 1] = vv.y;
        xs[w][m0*66 + in + 2] = vv.z;
        xs[w][m0*66 + in + 3] = vv.w;
    }
    wfence();

    const int a  = t >> 3, c = t & 7;
    const int x_ = a >> 1, h1 = a & 1;
    const int y_ = c >> 1, h2 = c & 1;

    float y3[8];

    mode_proj(xs[w], t1[w], t2[w], Wq0, Wq1, Wq2, bq, t, y3);
    #pragma unroll
    for (int h3 = 0; h3 < 2; ++h3) {
        const int h = (((h1 << 1) | h2) << 1) | h3;
        ushort4 v;
        v.x = f2bf(y3[0 + h3]); v.y = f2bf(y3[2 + h3]);
        v.z = f2bf(y3[4 + h3]); v.w = f2bf(y3[6 + h3]);
        *reinterpret_cast<ushort4*>(
            Qo + ((size_t)(b*NH_ + h)*SP_ + s)*HD_ + (x_*16 + y_*4)) = v;
    }
    mode_proj(xs[w], t1[w], t2[w], Wk0, Wk1, Wk2, bk, t, y3);
    #pragma unroll
    for (int h3 = 0; h3 < 2; ++h3) {
        const int h = (((h1 << 1) | h2) << 1) | h3;
        ushort4 v;
        v.x = f2bf(y3[0 + h3]); v.y = f2bf(y3[2 + h3]);
        v.z = f2bf(y3[4 + h3]); v.w = f2bf(y3[6 + h3]);
        *reinterpret_cast<ushort4*>(
            Ko + ((size_t)(b*NH_ + h)*SP_ + s)*HD_ + (x_*16 + y_*4)) = v;
    }
    mode_proj(xs[w], t1[w], t2[w], Wv0, Wv1, Wv2, bv, t, y3);
    #pragma unroll
    for (int h3 = 0; h3 < 2; ++h3) {
        const int h = (((h1 << 1) | h2) << 1) | h3;
        ushort4 v;
        v.x = f2bf(y3[0 + h3]); v.y = f2bf(y3[2 + h3]);
        v.z = f2bf(y3[4 + h3]); v.w = f2bf(y3[6 + h3]);
        *reinterpret_cast<ushort4*>(
            Vo + ((size_t)(b*NH_ + h)*SP_ + s)*HD_ + (x_*16 + y_*4)) = v;
    }
}

// ---------- kernel 2: MFMA attention, one block per (b,h), 8 waves, 1 strip/wave ----------
// S^T tile = mfma(A=K, B=Q): D col = query (lane&31), row = key (reg pattern)
// O  tile  = mfma(A=P, B=V): D col = dim   (lane&31), row = query
__global__ __launch_bounds__(512, 2) void k_attn(
    const u16* __restrict__ Q, const u16* __restrict__ K,
    const u16* __restrict__ V, u16* __restrict__ O)
{
    __shared__ u16   Kl[SP_*64];     // row-major, 16B-block XOR-swizzled: blk c -> c ^ (row&7)
    __shared__ u16   Vt[64*232];     // transposed [dim][tok], token stride padded to 232
    __shared__ float invl[8*32];

    const int bh  = blockIdx.x;
    const int tid = threadIdx.x;
    const u16* Qg = Q + (size_t)bh*SP_*HD_;
    const u16* Kg = K + (size_t)bh*SP_*HD_;
    const u16* Vg = V + (size_t)bh*SP_*HD_;

    // ---- stage K (swizzled 16B blocks; 1792 blocks of 16B) ----
    #pragma unroll
    for (int i = 0; i < 4; ++i) {
        int sIdx = i*512 + tid;
        if (sIdx < 1792) {
            int row = sIdx >> 3, cc = sIdx & 7;
            u32x4 d = *(const u32x4*)(Kg + sIdx*8);
            *(u32x4*)&Kl[row*64 + (cc ^ (row & 7))*8] = d;
        }
    }
    // ---- stage V transposed: 448 groups of (4 toks x 8 dims) ----
    if (tid < 448) {
        int tokg = tid >> 3, dg = tid & 7;
        int t0 = tokg*4, d0 = dg*8;
        u32x4 r0 = *(const u32x4*)(Vg + (size_t)(t0+0)*64 + d0);
        u32x4 r1 = *(const u32x4*)(Vg + (size_t)(t0+1)*64 + d0);
        u32x4 r2 = *(const u32x4*)(Vg + (size_t)(t0+2)*64 + d0);
        u32x4 r3 = *(const u32x4*)(Vg + (size_t)(t0+3)*64 + d0);
        #pragma unroll
        for (int j = 0; j < 8; ++j) {
            u32 sel = (j & 1) ? 0x07060302u : 0x05040100u;
            u32 lo  = __builtin_amdgcn_perm(r1[j>>1], r0[j>>1], sel);
            u32 hi2 = __builtin_amdgcn_perm(r3[j>>1], r2[j>>1], sel);
            *(u32x2*)&Vt[(d0+j)*232 + t0] = (u32x2){lo, hi2};
        }
    }
    __syncthreads();

    const int w    = tid >> 6;
    const int lane = tid & 63;
    const int l31  = lane & 31;
    const int hi   = lane >> 5;
    if (w >= 7) return;               // no barriers after this point
    const int strip = w;

    // Q B-frags for this strip (row = query = l31, k-dims contiguous)
    const u16* qb = Qg + (size_t)(strip*32 + l31)*64 + hi*8;
    const s16x8 qf0 = *(const s16x8*)(qb +  0);
    const s16x8 qf1 = *(const s16x8*)(qb + 16);
    const s16x8 qf2 = *(const s16x8*)(qb + 32);
    const s16x8 qf3 = *(const s16x8*)(qb + 48);

    f32x16 oacc0 = {}, oacc1 = {};
    float  psum  = 0.f;
    const int swz = l31 & 7;

    #pragma unroll
    for (int kt = 0; kt < 7; ++kt) {
        const u16* kbase = &Kl[(kt*32 + l31)*64];
        f32x16 sacc = {};
        s16x8 kf;
        kf = *(const s16x8*)(kbase + ((0 + hi) ^ swz)*8);
        sacc = __builtin_amdgcn_mfma_f32_32x32x16_bf16(kf, qf0, sacc, 0, 0, 0);
        kf = *(const s16x8*)(kbase + ((2 + hi) ^ swz)*8);
        sacc = __builtin_amdgcn_mfma_f32_32x32x16_bf16(kf, qf1, sacc, 0, 0, 0);
        kf = *(const s16x8*)(kbase + ((4 + hi) ^ swz)*8);
        sacc = __builtin_amdgcn_mfma_f32_32x32x16_bf16(kf, qf2, sacc, 0, 0, 0);
        kf = *(const s16x8*)(kbase + ((6 + hi) ^ swz)*8);
        sacc = __builtin_amdgcn_mfma_f32_32x32x16_bf16(kf, qf3, sacc, 0, 0, 0);

        // softmax numerators (fixed shift 0: logits are tiny)
        float p[16];
        #pragma unroll
        for (int r = 0; r < 16; ++r) p[r] = exp2f(sacc[r] * KSC);
        if (kt == 6) {                // keys 192+krow; valid < 210 <=> krow < 18
            const float hm = hi ? 0.f : 1.f;
            p[8] *= hm; p[9] *= hm;   // krow 16,17 (+4 if hi)
            p[10] = 0.f; p[11] = 0.f; p[12] = 0.f; p[13] = 0.f; p[14] = 0.f; p[15] = 0.f;
        }
        #pragma unroll
        for (int r = 0; r < 16; ++r) psum += p[r];

        // P (D-layout) -> A-frags via cvt_pk + permlane32_swap
        u32 c0, c1, c2, c3, c4, c5, c6, c7;
        asm("v_cvt_pk_bf16_f32 %0, %1, %2" : "=v"(c0) : "v"(p[0]),  "v"(p[1]));
        asm("v_cvt_pk_bf16_f32 %0, %1, %2" : "=v"(c1) : "v"(p[2]),  "v"(p[3]));
        asm("v_cvt_pk_bf16_f32 %0, %1, %2" : "=v"(c2) : "v"(p[4]),  "v"(p[5]));
        asm("v_cvt_pk_bf16_f32 %0, %1, %2" : "=v"(c3) : "v"(p[6]),  "v"(p[7]));
        asm("v_cvt_pk_bf16_f32 %0, %1, %2" : "=v"(c4) : "v"(p[8]),  "v"(p[9]));
        asm("v_cvt_pk_bf16_f32 %0, %1, %2" : "=v"(c5) : "v"(p[10]), "v"(p[11]));
        asm("v_cvt_pk_bf16_f32 %0, %1, %2" : "=v"(c6) : "v"(p[12]), "v"(p[13]));
        asm("v_cvt_pk_bf16_f32 %0, %1, %2" : "=v"(c7) : "v"(p[14]), "v"(p[15]));
        asm("v_permlane32_swap_b32 %0, %1" : "+v"(c0), "+v"(c2));
        asm("v_permlane32_swap_b32 %0, %1" : "+v"(c1), "+v"(c3));
        asm("v_permlane32_swap_b32 %0, %1" : "+v"(c4), "+v"(c6));
        asm("v_permlane32_swap_b32 %0, %1" : "+v"(c5), "+v"(c7));
        const s16x8 pf0 = __builtin_bit_cast(s16x8, (u32x4){c0, c1, c2, c3});
        const s16x8 pf1 = __builtin_bit_cast(s16x8, (u32x4){c4, c5, c6, c7});

        // PV: B-frag = 8 consecutive tokens of one dim row in Vt
        const u16* vb = &Vt[kt*32 + hi*8];
        s16x8 vf;
        vf = *(const s16x8*)(vb + (0*32 + l31)*232 +  0);
        oacc0 = __builtin_amdgcn_mfma_f32_32x32x16_bf16(pf0, vf, oacc0, 0, 0, 0);
        vf = *(const s16x8*)(vb + (0*32 + l31)*232 + 16);
        oacc0 = __builtin_amdgcn_mfma_f32_32x32x16_bf16(pf1, vf, oacc0, 0, 0, 0);
        vf = *(const s16x8*)(vb + (1*32 + l31)*232 +  0);
        oacc1 = __builtin_amdgcn_mfma_f32_32x32x16_bf16(pf0, vf, oacc1, 0, 0, 0);
        vf = *(const s16x8*)(vb + (1*32 + l31)*232 + 16);
        oacc1 = __builtin_amdgcn_mfma_f32_32x32x16_bf16(pf1, vf, oacc1, 0, 0, 0);
    }

    // ---- normalize + store (O row-major [bh][tok(S_)][dim]) ----
    float tot = psum + __shfl_xor(psum, 32, 64);
    invl[w*32 + l31] = 1.0f / tot;
    asm volatile("s_waitcnt lgkmcnt(0)" ::: "memory");

    u16* Ob = O + ((size_t)bh*S_ + strip*32)*HD_;
    #pragma unroll
    for (int r = 0; r < 16; ++r) {
        const int q = (r & 3) + 8*(r >> 2) + 4*hi;
        if (strip == 6 && q >= 18) continue;        // token >= 210
        const float iv = invl[w*32 + q];
        Ob[(size_t)q*64 + l31]      = f2bf(oacc0[r] * iv);
        Ob[(size_t)q*64 + 32 + l31] = f2bf(oacc1[r] * iv);
    }
}

// ---------- kernel 3: gather heads -> output projection -> f32 out (4 tokens/block) ----------
__global__ __launch_bounds__(256) void k_oproj(
    const u16* __restrict__ O,
    const float* __restrict__ Wo0, const float* __restrict__ Wo1,
    const float* __restrict__ Wo2, const float* __restrict__ bo,
    float* __restrict__ out)
{
    __shared__ float xs[4][528];
    __shared__ float t1[4][544];
    __shared__ float t2[4][576];
    const int w = threadIdx.x >> 6, t = threadIdx.x & 63;
    const int tok = blockIdx.x*4 + w;
    const int b   = tok / S_;
    const int s   = tok - b * S_;

    const int a  = t >> 3, c = t & 7;
    const int x_ = a >> 1, h1 = a & 1;
    const int y_ = c >> 1, h2 = c & 1;
    #pragma unroll
    for (int h3 = 0; h3 < 2; ++h3) {
        const int h = (((h1 << 1) | h2) << 1) | h3;
        const ushort4 v = *reinterpret_cast<const ushort4*>(
            O + ((size_t)(b*NH_ + h)*S_ + s)*HD_ + (x_*16 + y_*4));
        xs[w][a*66 + c*8 + 0 + h3] = bf2f(v.x);
        xs[w][a*66 + c*8 + 2 + h3] = bf2f(v.y);
        xs[w][a*66 + c*8 + 4 + h3] = bf2f(v.z);
        xs[w][a*66 + c*8 + 6 + h3] = bf2f(v.w);
    }
    wfence();

    float y3[8];
    mode_proj(xs[w], t1[w], t2[w], Wo0, Wo1, Wo2, bo, t, y3);

    float4* op = reinterpret_cast<float4*>(out + (size_t)tok * E_ + t * 8);
    float4 u0, u1;
    u0.x = y3[0]; u0.y = y3[1]; u0.z = y3[2]; u0.w = y3[3];
    u1.x = y3[4]; u1.y = y3[5]; u1.z = y3[6]; u1.w = y3[7];
    op[0] = u0;
    op[1] = u1;
}

extern "C" void kernel_launch(void* const* d_in, const int* in_sizes, int n_in,
                              void* d_out, int out_size, void* d_ws, size_t ws_size,
                              hipStream_t stream)
{
    const float* x   = (const float*)d_in[0];
    const float* Wq0 = (const float*)d_in[1];
    const float* Wq1 = (const float*)d_in[2];
    const float* Wq2 = (const float*)d_in[3];
    const float* bq  = (const float*)d_in[4];
    const float* Wk0 = (const float*)d_in[5];
    const float* Wk1 = (const float*)d_in[6];
    const float* Wk2 = (const float*)d_in[7];
    const float* bk  = (const float*)d_in[8];
    const float* Wv0 = (const float*)d_in[9];
    const float* Wv1 = (const float*)d_in[10];
    const float* Wv2 = (const float*)d_in[11];
    const float* bv  = (const float*)d_in[12];
    const float* Wo0 = (const float*)d_in[13];
    const float* Wo1 = (const float*)d_in[14];
    const float* Wo2 = (const float*)d_in[15];
    const float* bo  = (const float*)d_in[16];

    const size_t TP = (size_t)B_ * NH_ * SP_ * HD_;   // padded Q/K/V tensors
    u16* Qs = (u16*)d_ws;
    u16* Ks = Qs + TP;
    u16* Vs = Ks + TP;
    u16* Os = Vs + TP;                                // O: B_*NH_*S_*HD_

    k_qkv<<<NT_/4, 256, 0, stream>>>(x, Wq0, Wq1, Wq2, bq,
                                     Wk0, Wk1, Wk2, bk,
                                     Wv0, Wv1, Wv2, bv, Qs, Ks, Vs);
    k_attn<<<B_*NH_, 512, 0, stream>>>(Qs, Ks, Vs, Os);
    k_oproj<<<NT_/4, 256, 0, stream>>>(Os, Wo0, Wo1, Wo2, bo, (float*)d_out);
}